// Round 13
// baseline (221.618 us; speedup 1.0000x reference)
//
#include <hip/hip_runtime.h>

#define BB 16
#define NQn 8
#define NK 4096
#define CC 256
#define NHEADS 8
#define CIn 128
#define HDn 16
#define NHQ 64
#define EPS_TINY 1.17549435e-38f

// workspace float offsets
constexpr size_t OFF_QK   = 0;                                   // B*C*NHQ
constexpr size_t OFF_QBK  = OFF_QK  + (size_t)BB*CC*NHQ;         // B*NHQ
constexpr size_t OFF_SC   = OFF_QBK + (size_t)BB*NHQ;            // B*NK*NHQ (raw scores)
constexpr size_t OFF_MP   = OFF_SC  + (size_t)BB*NK*NHQ;         // B*64*NHQ
constexpr size_t OFF_SP   = OFF_MP  + (size_t)BB*64*NHQ;         // B*64*NHQ
constexpr size_t OFF_M    = OFF_SP  + (size_t)BB*64*NHQ;         // B*NHQ
constexpr size_t OFF_RS   = OFF_M   + (size_t)BB*NHQ;
constexpr size_t OFF_AVP  = OFF_RS  + (size_t)BB*NHQ;            // B*32*NHQ*C
constexpr size_t OFF_QATT = OFF_AVP + (size_t)BB*32*NHQ*CC;      // B*NQ*C
constexpr size_t OFF_UNC  = OFF_QATT+ (size_t)BB*NQn*CC;         // B*C
constexpr size_t OFF_REFT = OFF_UNC + (size_t)BB*CC;             // B*C
constexpr size_t OFF_RMAP = OFF_REFT+ (size_t)BB*CC;             // B*NK
constexpr size_t OFF_IDX  = OFF_RMAP+ (size_t)BB*NK;             // 128 ints
constexpr size_t OFF_RV   = OFF_IDX + 128;                       // 128 floats
constexpr size_t OFF_G    = OFF_RV  + 128;                       // B*NK*C

// K1: qh = (queries+query_pe)@Wq+bq (scaled by 1/4); fold Wk,bk into query side
__global__ __launch_bounds__(256) void k1_qside(
    const float* __restrict__ queries, const float* __restrict__ query_pe,
    const float* __restrict__ Wq, const float* __restrict__ bq,
    const float* __restrict__ Wk, const float* __restrict__ bk,
    float* __restrict__ ws)
{
  int b = blockIdx.x >> 3, q = blockIdx.x & 7, t = threadIdx.x;
  __shared__ float x[CC];
  __shared__ float qh[CIn];
  x[t] = queries[(b*NQn+q)*CC + t] + query_pe[(b*NQn+q)*CC + t];
  __syncthreads();
  if (t < CIn) {
    float a = bq[t];
    for (int c = 0; c < CC; ++c) a += x[c]*Wq[c*CIn + t];
    qh[t] = a * 0.25f;
  }
  __syncthreads();
  float* Qk = ws + OFF_QK;
  #pragma unroll
  for (int h = 0; h < NHEADS; ++h) {
    float a = 0.f;
    #pragma unroll
    for (int d = 0; d < HDn; ++d) a += qh[h*HDn+d] * Wk[t*CIn + h*HDn + d];
    Qk[((size_t)b*CC + t)*NHQ + h*NQn + q] = a;
  }
  if (t < NHEADS) {
    float a = 0.f;
    #pragma unroll
    for (int d = 0; d < HDn; ++d) a += qh[t*HDn+d] * bk[t*HDn+d];
    (ws + OFF_QBK)[b*NHQ + t*NQn + q] = a;
  }
}

// K2: fused G-materialization + scores GEMM + per-block softmax partials.
// (R10 proven version, ~95 us)
__global__ __launch_bounds__(256, 4) void k2_scores(
    const float* __restrict__ keys, const float* __restrict__ key_pe,
    const float* __restrict__ guiding, float* __restrict__ ws)
{
  int b = blockIdx.y, blk = blockIdx.x, n0 = blk * 64, t = threadIdx.x;
  __shared__ __align__(16) float Xs[64][36];   // [row][c_local]
  __shared__ __align__(16) float Qs[32][64];   // [c_local][hq]
  __shared__ float Gt[32][66];                 // guiding transpose [c_local][n_local]
  const float* Qk = ws + OFF_QK + (size_t)b*CC*NHQ;
  float* G = ws + OFF_G;
  const int tx = t & 15, ty = t >> 4;          // GEMM: rows 4ty.., hq 4tx..
  const int xr = t >> 2, xco = (t & 3) * 8;    // keys/pe staging
  const int gr = (t >> 6) * 8, gn = t & 63;    // guiding staging
  float acc[4][4] = {};

  float gld[8]; float4 k0v, k1v, p0v, p1v; float qp[8];
  // prologue: chunk 0 loads
  {
    #pragma unroll
    for (int i = 0; i < 8; ++i)
      gld[i] = guiding[((size_t)b*CC + gr + i)*NK + n0 + gn];
    size_t kb = ((size_t)b*NK + n0 + xr)*CC + xco;
    k0v = *(const float4*)&keys[kb];   k1v = *(const float4*)&keys[kb+4];
    p0v = *(const float4*)&key_pe[kb]; p1v = *(const float4*)&key_pe[kb+4];
    #pragma unroll
    for (int i = 0; i < 8; ++i) {
      int l = i*256 + t;
      qp[i] = Qk[(size_t)(l>>6)*NHQ + (l & 63)];
    }
  }
  for (int ch = 0; ch < 8; ++ch) {
    int c0 = ch*32;
    // P1: commit Gt
    #pragma unroll
    for (int i = 0; i < 8; ++i) Gt[gr + i][gn] = gld[i];
    __syncthreads();
    // P2: commit Qs; build Xs = keys*Gt + pe; write G
    #pragma unroll
    for (int i = 0; i < 8; ++i) {
      int l = i*256 + t;
      Qs[l>>6][l&63] = qp[i];
    }
    {
      size_t kbase = ((size_t)b*NK + n0 + xr)*CC + c0 + xco;
      float4 g0, g1;
      g0.x = k0v.x * Gt[xco+0][xr]; g0.y = k0v.y * Gt[xco+1][xr];
      g0.z = k0v.z * Gt[xco+2][xr]; g0.w = k0v.w * Gt[xco+3][xr];
      g1.x = k1v.x * Gt[xco+4][xr]; g1.y = k1v.y * Gt[xco+5][xr];
      g1.z = k1v.z * Gt[xco+6][xr]; g1.w = k1v.w * Gt[xco+7][xr];
      *(float4*)&G[kbase]   = g0;
      *(float4*)&G[kbase+4] = g1;
      float4 x0, x1;
      x0.x = g0.x+p0v.x; x0.y = g0.y+p0v.y; x0.z = g0.z+p0v.z; x0.w = g0.w+p0v.w;
      x1.x = g1.x+p1v.x; x1.y = g1.y+p1v.y; x1.z = g1.z+p1v.z; x1.w = g1.w+p1v.w;
      *(float4*)&Xs[xr][xco]   = x0;
      *(float4*)&Xs[xr][xco+4] = x1;
    }
    __syncthreads();
    // P3: issue next chunk's loads (fly during GEMM), then GEMM
    if (ch < 7) {
      int c1 = c0 + 32;
      #pragma unroll
      for (int i = 0; i < 8; ++i)
        gld[i] = guiding[((size_t)b*CC + c1 + gr + i)*NK + n0 + gn];
      size_t kb2 = ((size_t)b*NK + n0 + xr)*CC + c1 + xco;
      k0v = *(const float4*)&keys[kb2];   k1v = *(const float4*)&keys[kb2+4];
      p0v = *(const float4*)&key_pe[kb2]; p1v = *(const float4*)&key_pe[kb2+4];
      #pragma unroll
      for (int i = 0; i < 8; ++i) {
        int l = i*256 + t;
        qp[i] = Qk[(size_t)(c1 + (l>>6))*NHQ + (l & 63)];
      }
    }
    #pragma unroll 4
    for (int cb = 0; cb < 8; ++cb) {
      float4 xf[4];
      #pragma unroll
      for (int i = 0; i < 4; ++i) xf[i] = *(const float4*)&Xs[4*ty+i][4*cb];
      #pragma unroll
      for (int u = 0; u < 4; ++u) {
        float4 qf = *(const float4*)&Qs[4*cb+u][4*tx];
        float xu[4] = { ((const float*)&xf[0])[u], ((const float*)&xf[1])[u],
                        ((const float*)&xf[2])[u], ((const float*)&xf[3])[u] };
        #pragma unroll
        for (int i = 0; i < 4; ++i) {
          acc[i][0] += xu[i]*qf.x; acc[i][1] += xu[i]*qf.y;
          acc[i][2] += xu[i]*qf.z; acc[i][3] += xu[i]*qf.w;
        }
      }
    }
  }
  // epilogue: bias, write scores
  const float* qbk = ws + OFF_QBK + (size_t)b*NHQ;
  float qb[4] = {qbk[4*tx], qbk[4*tx+1], qbk[4*tx+2], qbk[4*tx+3]};
  float* scp = ws + OFF_SC + ((size_t)b*NK + n0)*NHQ;
  #pragma unroll
  for (int i = 0; i < 4; ++i) {
    acc[i][0] += qb[0]; acc[i][1] += qb[1]; acc[i][2] += qb[2]; acc[i][3] += qb[3];
    float4 o; o.x = acc[i][0]; o.y = acc[i][1]; o.z = acc[i][2]; o.w = acc[i][3];
    *(float4*)&scp[(size_t)(4*ty + i)*NHQ + 4*tx] = o;
  }
  // fused softmax partials for this 64-row block: max exact, sum grouped
  __syncthreads();
  float* red  = &Qs[0][0];               // [16][64]
  float* mfin = &Gt[0][0];               // [64]
  #pragma unroll
  for (int j = 0; j < 4; ++j) {
    float lm = fmaxf(fmaxf(acc[0][j], acc[1][j]), fmaxf(acc[2][j], acc[3][j]));
    red[ty*64 + 4*tx + j] = lm;
  }
  __syncthreads();
  if (t < 64) {
    float m = red[t];
    #pragma unroll
    for (int r = 1; r < 16; ++r) m = fmaxf(m, red[r*64 + t]);
    mfin[t] = m;
  }
  __syncthreads();
  #pragma unroll
  for (int j = 0; j < 4; ++j) {
    float m = mfin[4*tx + j];
    float ls = expf(acc[0][j]-m) + expf(acc[1][j]-m) + expf(acc[2][j]-m) + expf(acc[3][j]-m);
    red[ty*64 + 4*tx + j] = ls;
  }
  __syncthreads();
  if (t < 64) {
    float s = 0.f;
    #pragma unroll
    for (int r = 0; r < 16; ++r) s += red[r*64 + t];
    (ws + OFF_MP)[((size_t)b*64 + blk)*NHQ + t] = mfin[t];
    (ws + OFF_SP)[((size_t)b*64 + blk)*NHQ + t] = s;
  }
}

// K3b: combine 64 partials -> m, 1/s per (b,hq)  (R10 proven)
__global__ __launch_bounds__(64) void k3b_combine(float* __restrict__ ws)
{
  int b = blockIdx.x, hq = threadIdx.x;
  const float* mp = ws + OFF_MP + (size_t)b*64*NHQ;
  const float* sp = ws + OFF_SP + (size_t)b*64*NHQ;
  float m = -INFINITY;
  #pragma unroll 8
  for (int i = 0; i < 64; ++i) m = fmaxf(m, mp[i*NHQ+hq]);
  float s = 0.f;
  #pragma unroll 8
  for (int i = 0; i < 64; ++i) s += sp[i*NHQ+hq]*expf(mp[i*NHQ+hq]-m);
  (ws+OFF_M)[b*NHQ+hq] = m;
  (ws+OFF_RS)[b*NHQ+hq] = 1.0f/s;
}

// K4: AVpart[b][kbh][hq][cbase+c] = sum_{k in 128-row half} attn[k,hq]*G[k,c]
// Grid (32 kbh, 4 ch, 16 b) = 2048 blocks -> 8 blocks/CU (was grid-limited 4).
// SC and G each read once per element (same bytes as R10); W inline (bit-identical
// weights); k ascending within each half; k56 sums halves ascending (regroup).
__global__ __launch_bounds__(256) void k4_av(float* __restrict__ ws)
{
  int kbh = blockIdx.x, ch = blockIdx.y, b = blockIdx.z, t = threadIdx.x;
  int k0 = kbh * 128, cbase = ch * 64;
  __shared__ __align__(16) float gld[32][68];
  __shared__ __align__(16) float wld[32][64];
  __shared__ float mv[64], rv[64];
  if (t < 64) { mv[t] = (ws+OFF_M)[b*NHQ+t]; rv[t] = (ws+OFF_RS)[b*NHQ+t]; }
  int hq0 = (t & 15) * 4, c0 = (t >> 4) * 4;   // 4 hq x 4 c per thread
  int sr = t >> 4, sc4 = (t & 15) * 4;         // staging: 16 rows x 64 c per pass
  float accf[4][4] = {};
  const float* sc = ws + OFF_SC;
  const float* G  = ws + OFF_G;
  __syncthreads();   // mv/rv ready
  for (int kk = 0; kk < 128; kk += 32) {
    // P1: stage G tile + attention weights
    #pragma unroll
    for (int p = 0; p < 2; ++p)
      *(float4*)&gld[p*16 + sr][sc4] =
        *(const float4*)&G[((size_t)b*NK + k0+kk + p*16 + sr)*CC + cbase + sc4];
    #pragma unroll
    for (int i = 0; i < 8; ++i) {
      int l = i*256 + t; int k = l >> 6, hq = l & 63;
      float v = sc[((size_t)b*NK + k0+kk+k)*NHQ + hq];
      wld[k][hq] = expf(v - mv[hq]) * rv[hq];
    }
    __syncthreads();
    // P2: FMA
    #pragma unroll 4
    for (int k = 0; k < 32; ++k) {
      float4 w4 = *(const float4*)&wld[k][hq0];
      float4 gv = *(const float4*)&gld[k][c0];
      float wq[4] = {w4.x, w4.y, w4.z, w4.w};
      float gq[4] = {gv.x, gv.y, gv.z, gv.w};
      #pragma unroll
      for (int i = 0; i < 4; ++i)
        #pragma unroll
        for (int j = 0; j < 4; ++j) accf[i][j] += wq[i]*gq[j];
    }
    __syncthreads();
  }
  float* avp = ws + OFF_AVP + (((size_t)b*32 + kbh)*NHQ)*CC;
  #pragma unroll
  for (int i = 0; i < 4; ++i) {
    float4 o;
    o.x = accf[i][0]; o.y = accf[i][1]; o.z = accf[i][2]; o.w = accf[i][3];
    *(float4*)&avp[(size_t)(hq0 + i)*CC + cbase + c0] = o;
  }
}

// K56: reduce 32 AVpart halves (ascending), out = AV@Wv+bv, q_att = out@Wo+bo
__global__ __launch_bounds__(256) void k56_attout(
    const float* __restrict__ Wv, const float* __restrict__ bv,
    const float* __restrict__ Wo, const float* __restrict__ bo,
    float* __restrict__ ws)
{
  int b = blockIdx.x >> 3, q = blockIdx.x & 7, t = threadIdx.x;
  __shared__ float avs[NHEADS][CC];
  __shared__ float outv[CIn];
  const float* avp = ws + OFF_AVP;
  #pragma unroll
  for (int h = 0; h < NHEADS; ++h) {
    int hq = h*NQn + q;
    float a = 0.f;
    #pragma unroll 4
    for (int kb = 0; kb < 32; ++kb)
      a += avp[(((size_t)b*32 + kb)*NHQ + hq)*CC + t];
    avs[h][t] = a;
  }
  __syncthreads();
  if (t < CIn) {
    int h = t >> 4;
    float a = bv[t];
    for (int c = 0; c < CC; ++c) a += avs[h][c]*Wv[c*CIn + t];
    outv[t] = a;
  }
  __syncthreads();
  float a = bo[t];
  for (int ci = 0; ci < CIn; ++ci) a += outv[ci]*Wo[ci*CC + t];
  (ws+OFF_QATT)[((size_t)b*NQn + q)*CC + t] = a;
}

// K7: the two 3-layer MLPs on concat(static, q1)  (R10 proven)
__global__ __launch_bounds__(256) void k7_mlps(
    const float* __restrict__ su, const float* __restrict__ sr,
    const float* __restrict__ uW1, const float* __restrict__ ub1,
    const float* __restrict__ uW2, const float* __restrict__ ub2,
    const float* __restrict__ uW3, const float* __restrict__ ub3,
    const float* __restrict__ rW1, const float* __restrict__ rb1,
    const float* __restrict__ rW2, const float* __restrict__ rb2,
    const float* __restrict__ rW3, const float* __restrict__ rb3,
    float* __restrict__ ws)
{
  int b = blockIdx.x, t = threadIdx.x;
  __shared__ float xs[768];
  __shared__ float h1[2][64], h2[2][64];
  xs[t] = su[t];
  xs[256+t] = (ws+OFF_QATT)[((size_t)b*NQn + 1)*CC + t];
  xs[512+t] = sr[t];
  __syncthreads();
  if (t < 128) {
    int which = t >> 6, o = t & 63;
    const float* W1 = which ? rW1 : uW1;
    const float* b1 = which ? rb1 : ub1;
    int base = which ? 512 : 0;
    float a = b1[o];
    for (int i = 0; i < 256; ++i) a += xs[base+i]*W1[i*64 + o];
    for (int i = 0; i < 256; ++i) a += xs[256+i]*W1[(256+i)*64 + o];
    h1[which][o] = fmaxf(a, 0.f);
  }
  __syncthreads();
  if (t < 128) {
    int which = t >> 6, o = t & 63;
    const float* W2 = which ? rW2 : uW2;
    const float* b2 = which ? rb2 : ub2;
    float a = b2[o];
    #pragma unroll 8
    for (int i = 0; i < 64; ++i) a += h1[which][i]*W2[i*64+o];
    h2[which][o] = fmaxf(a, 0.f);
  }
  __syncthreads();
  {
    float a = ub3[t];
    #pragma unroll 8
    for (int i = 0; i < 64; ++i) a += h2[0][i]*uW3[i*CC + t];
    (ws+OFF_UNC)[b*CC + t] = a;
    float a2 = rb3[t];
    #pragma unroll 8
    for (int i = 0; i < 64; ++i) a2 += h2[1][i]*rW3[i*CC + t];
    (ws+OFF_REFT)[b*CC + t] = a2;
  }
}

// K8: three dots over c of G[b,n,:] with {q1, unc_tok, ref_tok}; ref_map
__global__ __launch_bounds__(256) void k8_masks(float* __restrict__ ws)
{
  int b = blockIdx.y, t = threadIdx.x;
  int wave = t >> 6, lane = t & 63;
  __shared__ float q1s[CC], us[CC], rts[CC];
  q1s[t] = (ws+OFF_QATT)[((size_t)b*NQn+1)*CC + t];
  us[t]  = (ws+OFF_UNC)[b*CC + t];
  rts[t] = (ws+OFF_REFT)[b*CC + t];
  __syncthreads();
  float q1v[4], usv[4], rtv[4];
  #pragma unroll
  for (int u = 0; u < 4; ++u) {
    q1v[u] = q1s[lane*4+u]; usv[u] = us[lane*4+u]; rtv[u] = rts[lane*4+u];
  }
  const float* G = ws + OFF_G;
  float* rmap = ws + OFF_RMAP + (size_t)b*NK;
  int n_base = blockIdx.x*32 + wave*8;
  for (int r = 0; r < 8; ++r) {
    int n = n_base + r;
    float4 gv = *(const float4*)&G[((size_t)b*NK + n)*CC + lane*4];
    float aq = gv.x*q1v[0] + gv.y*q1v[1] + gv.z*q1v[2] + gv.w*q1v[3];
    float au = gv.x*usv[0] + gv.y*usv[1] + gv.z*usv[2] + gv.w*usv[3];
    float ar = gv.x*rtv[0] + gv.y*rtv[1] + gv.z*rtv[2] + gv.w*rtv[3];
    #pragma unroll
    for (int s = 1; s < 64; s <<= 1) {
      aq += __shfl_xor(aq, s, 64);
      au += __shfl_xor(au, s, 64);
      ar += __shfl_xor(ar, s, 64);
    }
    if (lane == 0) {
      float un = 1.f/(1.f+expf(-au));
      rmap[n] = un * (1.f/(1.f+expf(-ar)) - 1.f/(1.f+expf(-aq)));
    }
  }
}

// K9: gumbel-softmax iterative top-4; wave-shfl reductions (R10 proven)
__global__ __launch_bounds__(256) void k9_gumbel(
    const float* __restrict__ gp, const float* __restrict__ gn,
    float* __restrict__ ws)
{
  int sign = blockIdx.x, b = blockIdx.y, t = threadIdx.x;
  int wave = t >> 6, lane = t & 63;
  const float* noise = sign ? gn : gp;
  const float* rmap = ws + OFF_RMAP + (size_t)b*NK;
  float g[16], kh[16], oh[16];
  #pragma unroll
  for (int i = 0; i < 16; ++i) {
    int n = i*256 + t;
    float scv = rmap[n];
    if (sign) scv = -scv;
    g[i] = scv + noise[(size_t)b*NK + n];
    kh[i] = 0.f; oh[i] = 0.f;
  }
  __shared__ float wred[8];
  __shared__ float selV[16];
  __shared__ int   selIdx[16];
  for (int it = 0; it < 4; ++it) {
    if (it > 0) {
      #pragma unroll
      for (int i = 0; i < 16; ++i) g[i] += logf(fmaxf(1.f - oh[i], EPS_TINY));
    }
    float m = g[0];
    #pragma unroll
    for (int i = 1; i < 16; ++i) m = fmaxf(m, g[i]);
    #pragma unroll
    for (int s = 1; s < 64; s <<= 1) m = fmaxf(m, __shfl_xor(m, s, 64));
    if (lane == 0) wred[wave] = m;
    __syncthreads();
    m = fmaxf(fmaxf(wred[0], wred[1]), fmaxf(wred[2], wred[3]));
    float e[16], ls = 0.f;
    #pragma unroll
    for (int i = 0; i < 16; ++i) { e[i] = expf(g[i]-m); ls += e[i]; }
    #pragma unroll
    for (int s = 1; s < 64; s <<= 1) ls += __shfl_xor(ls, s, 64);
    if (lane == 0) wred[4+wave] = ls;
    __syncthreads();
    float ssum = wred[4]+wred[5]+wred[6]+wred[7];
    #pragma unroll
    for (int i = 0; i < 16; ++i) { oh[i] = e[i]/ssum; kh[i] += oh[i]; }
  }
  int id[4]; float rr[4];
  for (int j = 0; j < 4; ++j) {
    float bv = kh[0]; int bi = t;
    #pragma unroll
    for (int i = 1; i < 16; ++i) {
      if (kh[i] > bv) { bv = kh[i]; bi = i*256 + t; }
    }
    #pragma unroll
    for (int s = 1; s < 64; s <<= 1) {
      float ov = __shfl_xor(bv, s, 64);
      int   oi = __shfl_xor(bi, s, 64);
      if (ov > bv || (ov == bv && oi < bi)) { bv = ov; bi = oi; }
    }
    if (lane == 0) { selV[j*4+wave] = bv; selIdx[j*4+wave] = bi; }
    __syncthreads();
    bv = selV[j*4]; bi = selIdx[j*4];
    #pragma unroll
    for (int w = 1; w < 4; ++w) {
      float ov = selV[j*4+w]; int oi = selIdx[j*4+w];
      if (ov > bv || (ov == bv && oi < bi)) { bv = ov; bi = oi; }
    }
    id[j] = bi; rr[j] = (1.f - bv) + bv;
    if ((bi & 255) == t) kh[bi >> 8] = -1.f;
  }
  if (t == 0) {
    for (int a = 0; a < 3; ++a)
      for (int c2 = a+1; c2 < 4; ++c2)
        if (id[c2] < id[a]) { int ti=id[a]; id[a]=id[c2]; id[c2]=ti; float tr=rr[a]; rr[a]=rr[c2]; rr[c2]=tr; }
    int* iout = (int*)(ws + OFF_IDX);
    float* rout = ws + OFF_RV;
    for (int j = 0; j < 4; ++j) {
      iout[(sign*BB + b)*4 + j] = id[j];
      rout[(sign*BB + b)*4 + j] = rr[j];
    }
  }
}

// K10: assemble (b, 32, 256) output
__global__ __launch_bounds__(256) void k10_out(
    const float* __restrict__ keys, const float* __restrict__ query_pe,
    const float* __restrict__ point_pos, const float* __restrict__ point_neg,
    const float* __restrict__ pe_gauss,
    float* __restrict__ ws, float* __restrict__ out)
{
  int b = blockIdx.y, r = blockIdx.x, t = threadIdx.x;
  const float* G = ws + OFF_G;
  float val;
  if (r < 8) {
    val = (r == 1) ? (ws+OFF_REFT)[b*CC + t]
                   : (ws+OFF_QATT)[((size_t)b*NQn + r)*CC + t];
  } else if (r < 16) {
    int j = r - 8; int sign = j >> 2; int jj = j & 3;
    int idx = ((const int*)(ws+OFF_IDX))[(sign*BB + b)*4 + jj];
    float rvv = (ws+OFF_RV)[(sign*BB + b)*4 + jj];
    float kv = keys[((size_t)b*NK + idx)*CC + t];
    float gv = G[((size_t)b*NK + idx)*CC + t];
    val = (kv + gv) * rvv;
  } else if (r < 24) {
    val = query_pe[((size_t)b*NQn + (r-16))*CC + t];
  } else {
    int j = r - 24; int sign = j >> 2; int jj = j & 3;
    int idx = ((const int*)(ws+OFF_IDX))[(sign*BB + b)*4 + jj];
    float rvv = (ws+OFF_RV)[(sign*BB + b)*4 + jj];
    const float* point = sign ? point_neg : point_pos;
    int h = idx >> 6, w = idx & 63;
    float x = (w + 0.5f)/64.f, y = (h + 0.5f)/64.f;
    int jf = (t < 128) ? t : (t - 128);
    float proj = ((2.f*x - 1.f)*pe_gauss[jf] + (2.f*y - 1.f)*pe_gauss[128 + jf]) * 6.28318530717958647692f;
    float sv = (t < 128) ? sinf(proj) : cosf(proj);
    val = sv*rvv + point[t];
  }
  out[((size_t)b*32 + r)*CC + t] = val;
}

extern "C" void kernel_launch(void* const* d_in, const int* in_sizes, int n_in,
                              void* d_out, int out_size, void* d_ws, size_t ws_size,
                              hipStream_t stream)
{
  const float* queries   = (const float*)d_in[0];
  const float* keys      = (const float*)d_in[1];
  const float* query_pe  = (const float*)d_in[2];
  const float* key_pe    = (const float*)d_in[3];
  const float* guiding   = (const float*)d_in[4];
  const float* gumbel_p  = (const float*)d_in[5];
  const float* gumbel_n  = (const float*)d_in[6];
  const float* s_unc     = (const float*)d_in[7];
  const float* s_ref     = (const float*)d_in[8];
  const float* Wq  = (const float*)d_in[9];   const float* bq  = (const float*)d_in[10];
  const float* Wk  = (const float*)d_in[11];  const float* bk  = (const float*)d_in[12];
  const float* Wv  = (const float*)d_in[13];  const float* bv  = (const float*)d_in[14];
  const float* Wo  = (const float*)d_in[15];  const float* bo  = (const float*)d_in[16];
  const float* uW1 = (const float*)d_in[17];  const float* ub1 = (const float*)d_in[18];
  const float* uW2 = (const float*)d_in[19];  const float* ub2 = (const float*)d_in[20];
  const float* uW3 = (const float*)d_in[21];  const float* ub3 = (const float*)d_in[22];
  const float* rW1 = (const float*)d_in[23];  const float* rb1 = (const float*)d_in[24];
  const float* rW2 = (const float*)d_in[25];  const float* rb2 = (const float*)d_in[26];
  const float* rW3 = (const float*)d_in[27];  const float* rb3 = (const float*)d_in[28];
  const float* pe_gauss  = (const float*)d_in[29];
  const float* point_pos = (const float*)d_in[30];
  const float* point_neg = (const float*)d_in[31];
  float* ws = (float*)d_ws;
  float* out = (float*)d_out;

  k1_qside  <<<dim3(BB*NQn),    256, 0, stream>>>(queries, query_pe, Wq, bq, Wk, bk, ws);
  k2_scores <<<dim3(64, BB),    256, 0, stream>>>(keys, key_pe, guiding, ws);
  k3b_combine<<<dim3(BB),        64, 0, stream>>>(ws);
  k4_av     <<<dim3(32, 4, BB), 256, 0, stream>>>(ws);
  k56_attout<<<dim3(BB*NQn),    256, 0, stream>>>(Wv, bv, Wo, bo, ws);
  k7_mlps   <<<dim3(BB),        256, 0, stream>>>(s_unc, s_ref, uW1, ub1, uW2, ub2, uW3, ub3,
                                                  rW1, rb1, rW2, rb2, rW3, rb3, ws);
  k8_masks  <<<dim3(128, BB),   256, 0, stream>>>(ws);
  k9_gumbel <<<dim3(2, BB),     256, 0, stream>>>(gumbel_p, gumbel_n, ws);
  k10_out   <<<dim3(32, BB),    256, 0, stream>>>(keys, query_pe, point_pos, point_neg,
                                                  pe_gauss, ws, out);
}

// Round 14
// 210.613 us; speedup vs baseline: 1.0523x; 1.0523x over previous
//
#include <hip/hip_runtime.h>

#define BB 16
#define NQn 8
#define NK 4096
#define CC 256
#define NHEADS 8
#define CIn 128
#define HDn 16
#define NHQ 64
#define EPS_TINY 1.17549435e-38f

// workspace float offsets
constexpr size_t OFF_QK   = 0;                                   // B*C*NHQ
constexpr size_t OFF_QBK  = OFF_QK  + (size_t)BB*CC*NHQ;         // B*NHQ
constexpr size_t OFF_SC   = OFF_QBK + (size_t)BB*NHQ;            // B*NK*NHQ (raw scores)
constexpr size_t OFF_MP   = OFF_SC  + (size_t)BB*NK*NHQ;         // B*64*NHQ
constexpr size_t OFF_SP   = OFF_MP  + (size_t)BB*64*NHQ;         // B*64*NHQ
constexpr size_t OFF_M    = OFF_SP  + (size_t)BB*64*NHQ;         // B*NHQ
constexpr size_t OFF_RS   = OFF_M   + (size_t)BB*NHQ;
constexpr size_t OFF_AVP  = OFF_RS  + (size_t)BB*NHQ;            // B*16*NHQ*C
constexpr size_t OFF_QATT = OFF_AVP + (size_t)BB*16*NHQ*CC;      // B*NQ*C
constexpr size_t OFF_UNC  = OFF_QATT+ (size_t)BB*NQn*CC;         // B*C
constexpr size_t OFF_REFT = OFF_UNC + (size_t)BB*CC;             // B*C
constexpr size_t OFF_RMAP = OFF_REFT+ (size_t)BB*CC;             // B*NK
constexpr size_t OFF_IDX  = OFF_RMAP+ (size_t)BB*NK;             // 128 ints
constexpr size_t OFF_RV   = OFF_IDX + 128;                       // 128 floats
constexpr size_t OFF_G    = OFF_RV  + 128;                       // B*NK*C

// K1: qh = (queries+query_pe)@Wq+bq (scaled by 1/4); fold Wk,bk into query side
__global__ __launch_bounds__(256) void k1_qside(
    const float* __restrict__ queries, const float* __restrict__ query_pe,
    const float* __restrict__ Wq, const float* __restrict__ bq,
    const float* __restrict__ Wk, const float* __restrict__ bk,
    float* __restrict__ ws)
{
  int b = blockIdx.x >> 3, q = blockIdx.x & 7, t = threadIdx.x;
  __shared__ float x[CC];
  __shared__ float qh[CIn];
  x[t] = queries[(b*NQn+q)*CC + t] + query_pe[(b*NQn+q)*CC + t];
  __syncthreads();
  if (t < CIn) {
    float a = bq[t];
    for (int c = 0; c < CC; ++c) a += x[c]*Wq[c*CIn + t];
    qh[t] = a * 0.25f;
  }
  __syncthreads();
  float* Qk = ws + OFF_QK;
  #pragma unroll
  for (int h = 0; h < NHEADS; ++h) {
    float a = 0.f;
    #pragma unroll
    for (int d = 0; d < HDn; ++d) a += qh[h*HDn+d] * Wk[t*CIn + h*HDn + d];
    Qk[((size_t)b*CC + t)*NHQ + h*NQn + q] = a;
  }
  if (t < NHEADS) {
    float a = 0.f;
    #pragma unroll
    for (int d = 0; d < HDn; ++d) a += qh[t*HDn+d] * bk[t*HDn+d];
    (ws + OFF_QBK)[b*NHQ + t*NQn + q] = a;
  }
}

// K2: fused G-materialization + scores GEMM + per-block softmax partials.
// 64-row tiles, 4x4 thread tile, 2 barriers/chunk, reg-prefetch one chunk ahead.
__global__ __launch_bounds__(256, 4) void k2_scores(
    const float* __restrict__ keys, const float* __restrict__ key_pe,
    const float* __restrict__ guiding, float* __restrict__ ws)
{
  int b = blockIdx.y, blk = blockIdx.x, n0 = blk * 64, t = threadIdx.x;
  __shared__ __align__(16) float Xs[64][36];   // [row][c_local]
  __shared__ __align__(16) float Qs[32][64];   // [c_local][hq]
  __shared__ float Gt[32][66];                 // guiding transpose [c_local][n_local]
  const float* Qk = ws + OFF_QK + (size_t)b*CC*NHQ;
  float* G = ws + OFF_G;
  const int tx = t & 15, ty = t >> 4;          // GEMM: rows 4ty.., hq 4tx..
  const int xr = t >> 2, xco = (t & 3) * 8;    // keys/pe staging
  const int gr = (t >> 6) * 8, gn = t & 63;    // guiding staging
  float acc[4][4] = {};

  float gld[8]; float4 k0v, k1v, p0v, p1v; float qp[8];
  // prologue: chunk 0 loads
  {
    #pragma unroll
    for (int i = 0; i < 8; ++i)
      gld[i] = guiding[((size_t)b*CC + gr + i)*NK + n0 + gn];
    size_t kb = ((size_t)b*NK + n0 + xr)*CC + xco;
    k0v = *(const float4*)&keys[kb];   k1v = *(const float4*)&keys[kb+4];
    p0v = *(const float4*)&key_pe[kb]; p1v = *(const float4*)&key_pe[kb+4];
    #pragma unroll
    for (int i = 0; i < 8; ++i) {
      int l = i*256 + t;
      qp[i] = Qk[(size_t)(l>>6)*NHQ + (l & 63)];
    }
  }
  for (int ch = 0; ch < 8; ++ch) {
    int c0 = ch*32;
    // P1: commit Gt
    #pragma unroll
    for (int i = 0; i < 8; ++i) Gt[gr + i][gn] = gld[i];
    __syncthreads();
    // P2: commit Qs; build Xs = keys*Gt + pe; write G
    #pragma unroll
    for (int i = 0; i < 8; ++i) {
      int l = i*256 + t;
      Qs[l>>6][l&63] = qp[i];
    }
    {
      size_t kbase = ((size_t)b*NK + n0 + xr)*CC + c0 + xco;
      float4 g0, g1;
      g0.x = k0v.x * Gt[xco+0][xr]; g0.y = k0v.y * Gt[xco+1][xr];
      g0.z = k0v.z * Gt[xco+2][xr]; g0.w = k0v.w * Gt[xco+3][xr];
      g1.x = k1v.x * Gt[xco+4][xr]; g1.y = k1v.y * Gt[xco+5][xr];
      g1.z = k1v.z * Gt[xco+6][xr]; g1.w = k1v.w * Gt[xco+7][xr];
      *(float4*)&G[kbase]   = g0;
      *(float4*)&G[kbase+4] = g1;
      float4 x0, x1;
      x0.x = g0.x+p0v.x; x0.y = g0.y+p0v.y; x0.z = g0.z+p0v.z; x0.w = g0.w+p0v.w;
      x1.x = g1.x+p1v.x; x1.y = g1.y+p1v.y; x1.z = g1.z+p1v.z; x1.w = g1.w+p1v.w;
      *(float4*)&Xs[xr][xco]   = x0;
      *(float4*)&Xs[xr][xco+4] = x1;
    }
    __syncthreads();
    // P3: issue next chunk's loads (fly during GEMM), then GEMM
    if (ch < 7) {
      int c1 = c0 + 32;
      #pragma unroll
      for (int i = 0; i < 8; ++i)
        gld[i] = guiding[((size_t)b*CC + c1 + gr + i)*NK + n0 + gn];
      size_t kb2 = ((size_t)b*NK + n0 + xr)*CC + c1 + xco;
      k0v = *(const float4*)&keys[kb2];   k1v = *(const float4*)&keys[kb2+4];
      p0v = *(const float4*)&key_pe[kb2]; p1v = *(const float4*)&key_pe[kb2+4];
      #pragma unroll
      for (int i = 0; i < 8; ++i) {
        int l = i*256 + t;
        qp[i] = Qk[(size_t)(c1 + (l>>6))*NHQ + (l & 63)];
      }
    }
    #pragma unroll 4
    for (int cb = 0; cb < 8; ++cb) {
      float4 xf[4];
      #pragma unroll
      for (int i = 0; i < 4; ++i) xf[i] = *(const float4*)&Xs[4*ty+i][4*cb];
      #pragma unroll
      for (int u = 0; u < 4; ++u) {
        float4 qf = *(const float4*)&Qs[4*cb+u][4*tx];
        float xu[4] = { ((const float*)&xf[0])[u], ((const float*)&xf[1])[u],
                        ((const float*)&xf[2])[u], ((const float*)&xf[3])[u] };
        #pragma unroll
        for (int i = 0; i < 4; ++i) {
          acc[i][0] += xu[i]*qf.x; acc[i][1] += xu[i]*qf.y;
          acc[i][2] += xu[i]*qf.z; acc[i][3] += xu[i]*qf.w;
        }
      }
    }
  }
  // epilogue: bias, write scores
  const float* qbk = ws + OFF_QBK + (size_t)b*NHQ;
  float qb[4] = {qbk[4*tx], qbk[4*tx+1], qbk[4*tx+2], qbk[4*tx+3]};
  float* scp = ws + OFF_SC + ((size_t)b*NK + n0)*NHQ;
  #pragma unroll
  for (int i = 0; i < 4; ++i) {
    acc[i][0] += qb[0]; acc[i][1] += qb[1]; acc[i][2] += qb[2]; acc[i][3] += qb[3];
    float4 o; o.x = acc[i][0]; o.y = acc[i][1]; o.z = acc[i][2]; o.w = acc[i][3];
    *(float4*)&scp[(size_t)(4*ty + i)*NHQ + 4*tx] = o;
  }
  // fused softmax partials for this 64-row block: max exact, sum grouped
  __syncthreads();
  float* red  = &Qs[0][0];               // [16][64]
  float* mfin = &Gt[0][0];               // [64]
  #pragma unroll
  for (int j = 0; j < 4; ++j) {
    float lm = fmaxf(fmaxf(acc[0][j], acc[1][j]), fmaxf(acc[2][j], acc[3][j]));
    red[ty*64 + 4*tx + j] = lm;
  }
  __syncthreads();
  if (t < 64) {
    float m = red[t];
    #pragma unroll
    for (int r = 1; r < 16; ++r) m = fmaxf(m, red[r*64 + t]);
    mfin[t] = m;
  }
  __syncthreads();
  #pragma unroll
  for (int j = 0; j < 4; ++j) {
    float m = mfin[4*tx + j];
    float ls = expf(acc[0][j]-m) + expf(acc[1][j]-m) + expf(acc[2][j]-m) + expf(acc[3][j]-m);
    red[ty*64 + 4*tx + j] = ls;
  }
  __syncthreads();
  if (t < 64) {
    float s = 0.f;
    #pragma unroll
    for (int r = 0; r < 16; ++r) s += red[r*64 + t];
    (ws + OFF_MP)[((size_t)b*64 + blk)*NHQ + t] = mfin[t];
    (ws + OFF_SP)[((size_t)b*64 + blk)*NHQ + t] = s;
  }
}

// K3b: combine 64 partials -> m, 1/s per (b,hq)
__global__ __launch_bounds__(64) void k3b_combine(float* __restrict__ ws)
{
  int b = blockIdx.x, hq = threadIdx.x;
  const float* mp = ws + OFF_MP + (size_t)b*64*NHQ;
  const float* sp = ws + OFF_SP + (size_t)b*64*NHQ;
  float m = -INFINITY;
  #pragma unroll 8
  for (int i = 0; i < 64; ++i) m = fmaxf(m, mp[i*NHQ+hq]);
  float s = 0.f;
  #pragma unroll 8
  for (int i = 0; i < 64; ++i) s += sp[i*NHQ+hq]*expf(mp[i*NHQ+hq]-m);
  (ws+OFF_M)[b*NHQ+hq] = m;
  (ws+OFF_RS)[b*NHQ+hq] = 1.0f/s;
}

// K4: AVpart[b][kb][hq][cbase+c] = sum_{k in kb block} attn[k,hq]*G[k,c]
// W computed inline during staging (bit-identical to softmax weights).
// grid (16 kb, 4 c-quarter, 16 b) = 1024 blocks, 256 thr, ~17 KB LDS.
__global__ __launch_bounds__(256) void k4_av(float* __restrict__ ws)
{
  int kb = blockIdx.x, ch = blockIdx.y, b = blockIdx.z, t = threadIdx.x;
  int k0 = kb * 256, cbase = ch * 64;
  __shared__ __align__(16) float gld[32][68];
  __shared__ __align__(16) float wld[32][64];
  __shared__ float mv[64], rv[64];
  if (t < 64) { mv[t] = (ws+OFF_M)[b*NHQ+t]; rv[t] = (ws+OFF_RS)[b*NHQ+t]; }
  int hq0 = (t & 15) * 4, c0 = (t >> 4) * 4;   // 4 hq x 4 c per thread
  int sr = t >> 4, sc4 = (t & 15) * 4;         // staging: 16 rows x 64 c per pass
  float accf[4][4] = {};
  const float* sc = ws + OFF_SC;
  const float* G  = ws + OFF_G;
  __syncthreads();   // mv/rv ready
  for (int kk = 0; kk < 256; kk += 32) {
    // P1: stage G tile + attention weights
    #pragma unroll
    for (int p = 0; p < 2; ++p)
      *(float4*)&gld[p*16 + sr][sc4] =
        *(const float4*)&G[((size_t)b*NK + k0+kk + p*16 + sr)*CC + cbase + sc4];
    #pragma unroll
    for (int i = 0; i < 8; ++i) {
      int l = i*256 + t; int k = l >> 6, hq = l & 63;
      float v = sc[((size_t)b*NK + k0+kk+k)*NHQ + hq];
      wld[k][hq] = expf(v - mv[hq]) * rv[hq];
    }
    __syncthreads();
    // P2: FMA
    #pragma unroll 4
    for (int k = 0; k < 32; ++k) {
      float4 w4 = *(const float4*)&wld[k][hq0];
      float4 gv = *(const float4*)&gld[k][c0];
      float wq[4] = {w4.x, w4.y, w4.z, w4.w};
      float gq[4] = {gv.x, gv.y, gv.z, gv.w};
      #pragma unroll
      for (int i = 0; i < 4; ++i)
        #pragma unroll
        for (int j = 0; j < 4; ++j) accf[i][j] += wq[i]*gq[j];
    }
    __syncthreads();
  }
  float* avp = ws + OFF_AVP + (((size_t)b*16 + kb)*NHQ)*CC;
  #pragma unroll
  for (int i = 0; i < 4; ++i) {
    float4 o;
    o.x = accf[i][0]; o.y = accf[i][1]; o.z = accf[i][2]; o.w = accf[i][3];
    *(float4*)&avp[(size_t)(hq0 + i)*CC + cbase + c0] = o;
  }
}

// K56: reduce AVpart, then out = AV@Wv+bv (per head), queries_att = out@Wo+bo
__global__ __launch_bounds__(256) void k56_attout(
    const float* __restrict__ Wv, const float* __restrict__ bv,
    const float* __restrict__ Wo, const float* __restrict__ bo,
    float* __restrict__ ws)
{
  int b = blockIdx.x >> 3, q = blockIdx.x & 7, t = threadIdx.x;
  __shared__ float avs[NHEADS][CC];
  __shared__ float outv[CIn];
  const float* avp = ws + OFF_AVP;
  #pragma unroll
  for (int h = 0; h < NHEADS; ++h) {
    int hq = h*NQn + q;
    float a = 0.f;
    #pragma unroll 4
    for (int kb = 0; kb < 16; ++kb)
      a += avp[(((size_t)b*16 + kb)*NHQ + hq)*CC + t];
    avs[h][t] = a;
  }
  __syncthreads();
  if (t < CIn) {
    int h = t >> 4;
    float a = bv[t];
    for (int c = 0; c < CC; ++c) a += avs[h][c]*Wv[c*CIn + t];
    outv[t] = a;
  }
  __syncthreads();
  float a = bo[t];
  for (int ci = 0; ci < CIn; ++ci) a += outv[ci]*Wo[ci*CC + t];
  (ws+OFF_QATT)[((size_t)b*NQn + q)*CC + t] = a;
}

// K7: the two 3-layer MLPs on concat(static, q1)
__global__ __launch_bounds__(256) void k7_mlps(
    const float* __restrict__ su, const float* __restrict__ sr,
    const float* __restrict__ uW1, const float* __restrict__ ub1,
    const float* __restrict__ uW2, const float* __restrict__ ub2,
    const float* __restrict__ uW3, const float* __restrict__ ub3,
    const float* __restrict__ rW1, const float* __restrict__ rb1,
    const float* __restrict__ rW2, const float* __restrict__ rb2,
    const float* __restrict__ rW3, const float* __restrict__ rb3,
    float* __restrict__ ws)
{
  int b = blockIdx.x, t = threadIdx.x;
  __shared__ float xs[768];
  __shared__ float h1[2][64], h2[2][64];
  xs[t] = su[t];
  xs[256+t] = (ws+OFF_QATT)[((size_t)b*NQn + 1)*CC + t];
  xs[512+t] = sr[t];
  __syncthreads();
  if (t < 128) {
    int which = t >> 6, o = t & 63;
    const float* W1 = which ? rW1 : uW1;
    const float* b1 = which ? rb1 : ub1;
    int base = which ? 512 : 0;
    float a = b1[o];
    for (int i = 0; i < 256; ++i) a += xs[base+i]*W1[i*64 + o];
    for (int i = 0; i < 256; ++i) a += xs[256+i]*W1[(256+i)*64 + o];
    h1[which][o] = fmaxf(a, 0.f);
  }
  __syncthreads();
  if (t < 128) {
    int which = t >> 6, o = t & 63;
    const float* W2 = which ? rW2 : uW2;
    const float* b2 = which ? rb2 : ub2;
    float a = b2[o];
    #pragma unroll 8
    for (int i = 0; i < 64; ++i) a += h1[which][i]*W2[i*64+o];
    h2[which][o] = fmaxf(a, 0.f);
  }
  __syncthreads();
  {
    float a = ub3[t];
    #pragma unroll 8
    for (int i = 0; i < 64; ++i) a += h2[0][i]*uW3[i*CC + t];
    (ws+OFF_UNC)[b*CC + t] = a;
    float a2 = rb3[t];
    #pragma unroll 8
    for (int i = 0; i < 64; ++i) a2 += h2[1][i]*rW3[i*CC + t];
    (ws+OFF_REFT)[b*CC + t] = a2;
  }
}

// K8: three dots over c of G[b,n,:] with {q1, unc_tok, ref_tok}; ref_map
__global__ __launch_bounds__(256) void k8_masks(float* __restrict__ ws)
{
  int b = blockIdx.y, t = threadIdx.x;
  int wave = t >> 6, lane = t & 63;
  __shared__ float q1s[CC], us[CC], rts[CC];
  q1s[t] = (ws+OFF_QATT)[((size_t)b*NQn+1)*CC + t];
  us[t]  = (ws+OFF_UNC)[b*CC + t];
  rts[t] = (ws+OFF_REFT)[b*CC + t];
  __syncthreads();
  float q1v[4], usv[4], rtv[4];
  #pragma unroll
  for (int u = 0; u < 4; ++u) {
    q1v[u] = q1s[lane*4+u]; usv[u] = us[lane*4+u]; rtv[u] = rts[lane*4+u];
  }
  const float* G = ws + OFF_G;
  float* rmap = ws + OFF_RMAP + (size_t)b*NK;
  int n_base = blockIdx.x*32 + wave*8;
  for (int r = 0; r < 8; ++r) {
    int n = n_base + r;
    float4 gv = *(const float4*)&G[((size_t)b*NK + n)*CC + lane*4];
    float aq = gv.x*q1v[0] + gv.y*q1v[1] + gv.z*q1v[2] + gv.w*q1v[3];
    float au = gv.x*usv[0] + gv.y*usv[1] + gv.z*usv[2] + gv.w*usv[3];
    float ar = gv.x*rtv[0] + gv.y*rtv[1] + gv.z*rtv[2] + gv.w*rtv[3];
    #pragma unroll
    for (int s = 1; s < 64; s <<= 1) {
      aq += __shfl_xor(aq, s, 64);
      au += __shfl_xor(au, s, 64);
      ar += __shfl_xor(ar, s, 64);
    }
    if (lane == 0) {
      float un = 1.f/(1.f+expf(-au));
      rmap[n] = un * (1.f/(1.f+expf(-ar)) - 1.f/(1.f+expf(-aq)));
    }
  }
}

// K9: gumbel-softmax iterative top-4; wave-shfl reductions
__global__ __launch_bounds__(256) void k9_gumbel(
    const float* __restrict__ gp, const float* __restrict__ gn,
    float* __restrict__ ws)
{
  int sign = blockIdx.x, b = blockIdx.y, t = threadIdx.x;
  int wave = t >> 6, lane = t & 63;
  const float* noise = sign ? gn : gp;
  const float* rmap = ws + OFF_RMAP + (size_t)b*NK;
  float g[16], kh[16], oh[16];
  #pragma unroll
  for (int i = 0; i < 16; ++i) {
    int n = i*256 + t;
    float scv = rmap[n];
    if (sign) scv = -scv;
    g[i] = scv + noise[(size_t)b*NK + n];
    kh[i] = 0.f; oh[i] = 0.f;
  }
  __shared__ float wred[8];
  __shared__ float selV[16];
  __shared__ int   selIdx[16];
  for (int it = 0; it < 4; ++it) {
    if (it > 0) {
      #pragma unroll
      for (int i = 0; i < 16; ++i) g[i] += logf(fmaxf(1.f - oh[i], EPS_TINY));
    }
    float m = g[0];
    #pragma unroll
    for (int i = 1; i < 16; ++i) m = fmaxf(m, g[i]);
    #pragma unroll
    for (int s = 1; s < 64; s <<= 1) m = fmaxf(m, __shfl_xor(m, s, 64));
    if (lane == 0) wred[wave] = m;
    __syncthreads();
    m = fmaxf(fmaxf(wred[0], wred[1]), fmaxf(wred[2], wred[3]));
    float e[16], ls = 0.f;
    #pragma unroll
    for (int i = 0; i < 16; ++i) { e[i] = expf(g[i]-m); ls += e[i]; }
    #pragma unroll
    for (int s = 1; s < 64; s <<= 1) ls += __shfl_xor(ls, s, 64);
    if (lane == 0) wred[4+wave] = ls;
    __syncthreads();
    float ssum = wred[4]+wred[5]+wred[6]+wred[7];
    #pragma unroll
    for (int i = 0; i < 16; ++i) { oh[i] = e[i]/ssum; kh[i] += oh[i]; }
  }
  int id[4]; float rr[4];
  for (int j = 0; j < 4; ++j) {
    float bv = kh[0]; int bi = t;
    #pragma unroll
    for (int i = 1; i < 16; ++i) {
      if (kh[i] > bv) { bv = kh[i]; bi = i*256 + t; }
    }
    #pragma unroll
    for (int s = 1; s < 64; s <<= 1) {
      float ov = __shfl_xor(bv, s, 64);
      int   oi = __shfl_xor(bi, s, 64);
      if (ov > bv || (ov == bv && oi < bi)) { bv = ov; bi = oi; }
    }
    if (lane == 0) { selV[j*4+wave] = bv; selIdx[j*4+wave] = bi; }
    __syncthreads();
    bv = selV[j*4]; bi = selIdx[j*4];
    #pragma unroll
    for (int w = 1; w < 4; ++w) {
      float ov = selV[j*4+w]; int oi = selIdx[j*4+w];
      if (ov > bv || (ov == bv && oi < bi)) { bv = ov; bi = oi; }
    }
    id[j] = bi; rr[j] = (1.f - bv) + bv;
    if ((bi & 255) == t) kh[bi >> 8] = -1.f;
  }
  if (t == 0) {
    for (int a = 0; a < 3; ++a)
      for (int c2 = a+1; c2 < 4; ++c2)
        if (id[c2] < id[a]) { int ti=id[a]; id[a]=id[c2]; id[c2]=ti; float tr=rr[a]; rr[a]=rr[c2]; rr[c2]=tr; }
    int* iout = (int*)(ws + OFF_IDX);
    float* rout = ws + OFF_RV;
    for (int j = 0; j < 4; ++j) {
      iout[(sign*BB + b)*4 + j] = id[j];
      rout[(sign*BB + b)*4 + j] = rr[j];
    }
  }
}

// K10: assemble (b, 32, 256) output
__global__ __launch_bounds__(256) void k10_out(
    const float* __restrict__ keys, const float* __restrict__ query_pe,
    const float* __restrict__ point_pos, const float* __restrict__ point_neg,
    const float* __restrict__ pe_gauss,
    float* __restrict__ ws, float* __restrict__ out)
{
  int b = blockIdx.y, r = blockIdx.x, t = threadIdx.x;
  const float* G = ws + OFF_G;
  float val;
  if (r < 8) {
    val = (r == 1) ? (ws+OFF_REFT)[b*CC + t]
                   : (ws+OFF_QATT)[((size_t)b*NQn + r)*CC + t];
  } else if (r < 16) {
    int j = r - 8; int sign = j >> 2; int jj = j & 3;
    int idx = ((const int*)(ws+OFF_IDX))[(sign*BB + b)*4 + jj];
    float rvv = (ws+OFF_RV)[(sign*BB + b)*4 + jj];
    float kv = keys[((size_t)b*NK + idx)*CC + t];
    float gv = G[((size_t)b*NK + idx)*CC + t];
    val = (kv + gv) * rvv;
  } else if (r < 24) {
    val = query_pe[((size_t)b*NQn + (r-16))*CC + t];
  } else {
    int j = r - 24; int sign = j >> 2; int jj = j & 3;
    int idx = ((const int*)(ws+OFF_IDX))[(sign*BB + b)*4 + jj];
    float rvv = (ws+OFF_RV)[(sign*BB + b)*4 + jj];
    const float* point = sign ? point_neg : point_pos;
    int h = idx >> 6, w = idx & 63;
    float x = (w + 0.5f)/64.f, y = (h + 0.5f)/64.f;
    int jf = (t < 128) ? t : (t - 128);
    float proj = ((2.f*x - 1.f)*pe_gauss[jf] + (2.f*y - 1.f)*pe_gauss[128 + jf]) * 6.28318530717958647692f;
    float sv = (t < 128) ? sinf(proj) : cosf(proj);
    val = sv*rvv + point[t];
  }
  out[((size_t)b*32 + r)*CC + t] = val;
}

extern "C" void kernel_launch(void* const* d_in, const int* in_sizes, int n_in,
                              void* d_out, int out_size, void* d_ws, size_t ws_size,
                              hipStream_t stream)
{
  const float* queries   = (const float*)d_in[0];
  const float* keys      = (const float*)d_in[1];
  const float* query_pe  = (const float*)d_in[2];
  const float* key_pe    = (const float*)d_in[3];
  const float* guiding   = (const float*)d_in[4];
  const float* gumbel_p  = (const float*)d_in[5];
  const float* gumbel_n  = (const float*)d_in[6];
  const float* s_unc     = (const float*)d_in[7];
  const float* s_ref     = (const float*)d_in[8];
  const float* Wq  = (const float*)d_in[9];   const float* bq  = (const float*)d_in[10];
  const float* Wk  = (const float*)d_in[11];  const float* bk  = (const float*)d_in[12];
  const float* Wv  = (const float*)d_in[13];  const float* bv  = (const float*)d_in[14];
  const float* Wo  = (const float*)d_in[15];  const float* bo  = (const float*)d_in[16];
  const float* uW1 = (const float*)d_in[17];  const float* ub1 = (const float*)d_in[18];
  const float* uW2 = (const float*)d_in[19];  const float* ub2 = (const float*)d_in[20];
  const float* uW3 = (const float*)d_in[21];  const float* ub3 = (const float*)d_in[22];
  const float* rW1 = (const float*)d_in[23];  const float* rb1 = (const float*)d_in[24];
  const float* rW2 = (const float*)d_in[25];  const float* rb2 = (const float*)d_in[26];
  const float* rW3 = (const float*)d_in[27];  const float* rb3 = (const float*)d_in[28];
  const float* pe_gauss  = (const float*)d_in[29];
  const float* point_pos = (const float*)d_in[30];
  const float* point_neg = (const float*)d_in[31];
  float* ws = (float*)d_ws;
  float* out = (float*)d_out;

  k1_qside  <<<dim3(BB*NQn),    256, 0, stream>>>(queries, query_pe, Wq, bq, Wk, bk, ws);
  k2_scores <<<dim3(64, BB),    256, 0, stream>>>(keys, key_pe, guiding, ws);
  k3b_combine<<<dim3(BB),        64, 0, stream>>>(ws);
  k4_av     <<<dim3(16, 4, BB), 256, 0, stream>>>(ws);
  k56_attout<<<dim3(BB*NQn),    256, 0, stream>>>(Wv, bv, Wo, bo, ws);
  k7_mlps   <<<dim3(BB),        256, 0, stream>>>(s_unc, s_ref, uW1, ub1, uW2, ub2, uW3, ub3,
                                                  rW1, rb1, rW2, rb2, rW3, rb3, ws);
  k8_masks  <<<dim3(128, BB),   256, 0, stream>>>(ws);
  k9_gumbel <<<dim3(2, BB),     256, 0, stream>>>(gumbel_p, gumbel_n, ws);
  k10_out   <<<dim3(32, BB),    256, 0, stream>>>(keys, query_pe, point_pos, point_neg,
                                                  pe_gauss, ws, out);
}